// Round 5
// baseline (295.308 us; speedup 1.0000x reference)
//
#include <hip/hip_runtime.h>
#include <hip/hip_bf16.h>
#include <stdint.h>

// MultiHeadAttentionNoScale: B=2, L=2048, D=1024, H=16, dk=64.
// R5: R3's proven staging (2-barrier, single K/V buffer) + rmb mask words applied
//     via inverse_ballot (1 cndmask per 64 elems, no inline asm) + ones-MFMA row
//     sums. R4's inline-asm cndmask and double-buffer are reverted (bisect).

typedef __bf16 bf16;
typedef __bf16 bf16x8 __attribute__((ext_vector_type(8)));
typedef float f32x4 __attribute__((ext_vector_type(4)));

#define AS1 __attribute__((address_space(1)))
#define AS3 __attribute__((address_space(3)))

__device__ __forceinline__ void g2l16(const void* g, void* l) {
    // async global->LDS, 16B per lane; LDS dest = wave-uniform base + lane*16
    __builtin_amdgcn_global_load_lds((AS1 void*)g, (AS3 void*)l, 16, 0, 0);
}

// true iff this lane's bit is set in wave-uniform mask m
__device__ __forceinline__ bool lane_masked(unsigned long long m) {
#if __has_builtin(__builtin_amdgcn_inverse_ballot_w64)
    return __builtin_amdgcn_inverse_ballot_w64(m);
#else
    return (m >> (threadIdx.x & 63)) & 1ull;
#endif
}

#define LOG2E 1.44269504088896f

// ---------------- fp32 -> bf16 convert (3 tensors, one launch) ----------------
__global__ __launch_bounds__(256) void cvt3_kernel(const float* __restrict__ a0,
                                                   const float* __restrict__ a1,
                                                   const float* __restrict__ a2,
                                                   bf16* o0, bf16* o1, bf16* o2) {
    int y = blockIdx.y;
    const float* in = (y == 0) ? a0 : (y == 1) ? a1 : a2;
    bf16* out = (y == 0) ? o0 : (y == 1) ? o1 : o2;
    int idx = blockIdx.x * 256 + threadIdx.x;
    float4 v = ((const float4*)in)[idx];
    __align__(8) bf16 o[4];
    o[0] = (bf16)v.x; o[1] = (bf16)v.y; o[2] = (bf16)v.z; o[3] = (bf16)v.w;
    *(uint2*)(out + (size_t)idx * 4) = *(const uint2*)o;
}

// ---------------- mask representation detect (int32 / uint8 / fp32) ----------------
__global__ __launch_bounds__(256) void mdetect_kernel(const unsigned int* __restrict__ w,
                                                      int* __restrict__ flag) {
    int idx = blockIdx.x * 256 + threadIdx.x;
    unsigned v = w[idx];
    int f = 0;
    if (v == 0x3F800000u) f = 2;        // float 1.0 pattern -> fp32 mask
    else if (v > 1u) f = 1;             // bytes packed -> uint8 mask
    unsigned long long b1 = __ballot(f & 1);
    unsigned long long b2 = __ballot(f & 2);
    if ((threadIdx.x & 63) == 0) {
        int agg = (b1 ? 1 : 0) | (b2 ? 2 : 0);
        if (agg) atomicOr(flag, agg);
    }
}

// ---------------- mask -> bitmask mb[row][kword], bit=1 means masked ----------------
__global__ __launch_bounds__(256) void mpack_kernel(const void* __restrict__ mask,
                                                    unsigned long long* __restrict__ mb,
                                                    const int* __restrict__ flag) {
    int idx = blockIdx.x * 256 + threadIdx.x;
    int f = *flag;
    bool v;
    if (f & 2)      v = ((const float*)mask)[idx] != 0.0f;
    else if (f & 1) v = ((const unsigned char*)mask)[idx] != 0;
    else            v = ((const int*)mask)[idx] != 0;
    unsigned long long b = __ballot(v);
    if ((threadIdx.x & 63) == 0) mb[idx >> 6] = b;
}

// ---------------- mb -> rmb: lane-bit layout for attn's C-fragment ----------------
// word(task=qg*32+kt, r, nt): bit(lane) = mask[qg*16 + (lane>>4)*4 + r][kt*64 + nt*16 + (lane&15)]
__global__ __launch_bounds__(256) void rpack_kernel(const unsigned long long* __restrict__ mb,
                                                    unsigned long long* __restrict__ rmb) {
    int task = blockIdx.x * 4 + (threadIdx.x >> 6);   // 0..4095
    int qg = task >> 5, kt = task & 31;
    int lane = threadIdx.x & 63, quad = lane >> 4, col = lane & 15;
    #pragma unroll
    for (int r = 0; r < 4; ++r) {
        unsigned long long wrow = mb[(size_t)(qg * 16 + quad * 4 + r) * 32 + kt];
        #pragma unroll
        for (int nt = 0; nt < 4; ++nt) {
            unsigned long long b = __ballot(((wrow >> (nt * 16 + col)) & 1ull) != 0);
            if (lane == 0) rmb[(size_t)task * 16 + r * 4 + nt] = b;
        }
    }
}

// ---------------- W [k][n] fp32 -> Wt [n][k] bf16 (64x64 LDS tile transpose) ----------------
__global__ __launch_bounds__(256) void wtrans_kernel(const float* W0, const float* W1,
                                                     const float* W2, const float* W3,
                                                     bf16* T0, bf16* T1, bf16* T2, bf16* T3) {
    const float* W; bf16* T;
    int y = blockIdx.y;
    if (y == 0)      { W = W0; T = T0; }
    else if (y == 1) { W = W1; T = T1; }
    else if (y == 2) { W = W2; T = T2; }
    else             { W = W3; T = T3; }
    int tx = blockIdx.x & 15, ty = blockIdx.x >> 4;
    int n0 = tx * 64, k0 = ty * 64;
    __shared__ __align__(16) bf16 t[64 * 72];   // [k][n], +8 pad
    int tid = threadIdx.x;
    #pragma unroll
    for (int rr = 0; rr < 4; ++rr) {
        int idx = rr * 256 + tid;
        int r = idx >> 4, c4 = (idx & 15) * 4;
        float4 v = *(const float4*)(W + (size_t)(k0 + r) * 1024 + n0 + c4);
        __align__(8) bf16 o[4];
        o[0] = (bf16)v.x; o[1] = (bf16)v.y; o[2] = (bf16)v.z; o[3] = (bf16)v.w;
        *(uint2*)&t[r * 72 + c4] = *(const uint2*)o;
    }
    __syncthreads();
    #pragma unroll
    for (int rr = 0; rr < 2; ++rr) {
        int idx = rr * 256 + tid;
        int n = idx >> 3, kc = (idx & 7) * 8;
        __align__(16) bf16 o[8];
        #pragma unroll
        for (int j = 0; j < 8; ++j) o[j] = t[(kc + j) * 72 + n];
        *(uint4*)(T + (size_t)(n0 + n) * 1024 + k0 + kc) = *(const uint4*)o;
    }
}

// ---------------- 128x128 bt-GEMM core ----------------
// C[m,n] = (sum_k A[m,k]*Bt[n,k] + bias[n]) * scale
// MODE 0: bf16 head-layout [b][h][l][dk]; MODE 2: bf16 V^T [b][h][dk][l]
template <int MODE>
__device__ __forceinline__ void gemm128_core(const bf16* __restrict__ A,
                                             const bf16* __restrict__ Bt,
                                             const float* __restrict__ bias,
                                             void* __restrict__ Out, int bm, int bn,
                                             float scale) {
    __shared__ __align__(16) bf16 la[128 * 32];
    __shared__ __align__(16) bf16 lb[128 * 32];
    int tid = threadIdx.x;
    int w = tid >> 6, lane = tid & 63;
    int quad = lane >> 4, col = lane & 15;
    int wm = w >> 1, wn = w & 1;
    int m0 = bm * 128, n0 = bn * 128;
    f32x4 acc[4][4];
    f32x4 z = {0.f, 0.f, 0.f, 0.f};
    #pragma unroll
    for (int i = 0; i < 4; ++i)
        #pragma unroll
        for (int j = 0; j < 4; ++j) acc[i][j] = z;
    int srow = lane >> 2;
    int skc = (lane & 3) * 8;
    for (int kt = 0; kt < 32; ++kt) {
        int kk = kt * 32;
        __syncthreads();
        #pragma unroll
        for (int rr = 0; rr < 2; ++rr) {
            int ch = rr * 4 + w;
            int row = ch * 16 + srow;
            g2l16(A + (size_t)(m0 + row) * 1024 + kk + skc, &la[ch * 512]);
            g2l16(Bt + (size_t)(n0 + row) * 1024 + kk + skc, &lb[ch * 512]);
        }
        __syncthreads();
        bf16x8 af[4], bfr[4];
        #pragma unroll
        for (int mt = 0; mt < 4; ++mt)
            af[mt] = *(const bf16x8*)&la[(wm * 64 + mt * 16 + col) * 32 + quad * 8];
        #pragma unroll
        for (int nt = 0; nt < 4; ++nt)
            bfr[nt] = *(const bf16x8*)&lb[(wn * 64 + nt * 16 + col) * 32 + quad * 8];
        #pragma unroll
        for (int mt = 0; mt < 4; ++mt)
            #pragma unroll
            for (int nt = 0; nt < 4; ++nt)
                acc[mt][nt] = __builtin_amdgcn_mfma_f32_16x16x32_bf16(
                    af[mt], bfr[nt], acc[mt][nt], 0, 0, 0);
    }
    float bia[4];
    #pragma unroll
    for (int nt = 0; nt < 4; ++nt) bia[nt] = bias[n0 + wn * 64 + nt * 16 + col];
    #pragma unroll
    for (int mt = 0; mt < 4; ++mt) {
        #pragma unroll
        for (int nt = 0; nt < 4; ++nt) {
            #pragma unroll
            for (int r = 0; r < 4; ++r) {
                int m = m0 + wm * 64 + mt * 16 + quad * 4 + r;
                int n = n0 + wn * 64 + nt * 16 + col;
                float v = (acc[mt][nt][r] + bia[nt]) * scale;
                if (MODE == 0) {
                    int b = m >> 11, l = m & 2047, h = n >> 6, d = n & 63;
                    ((bf16*)Out)[(((size_t)b * 16 + h) * 2048 + l) * 64 + d] = (bf16)v;
                } else {
                    int b = m >> 11, l = m & 2047, h = n >> 6, d = n & 63;
                    ((bf16*)Out)[(((size_t)b * 16 + h) * 64 + d) * 2048 + l] = (bf16)v;
                }
            }
        }
    }
}

// Q scaled by log2e (folded softmax base conversion); K,V unscaled; V -> V^T layout
__global__ __launch_bounds__(256) void qkv_kernel(
    const bf16* Xq, const bf16* Xk, const bf16* Xv,
    const bf16* Wq, const bf16* Wk, const bf16* Wv,
    const float* bq, const float* bk, const float* bv,
    bf16* Qh, bf16* Kh, bf16* Vt) {
    int y = blockIdx.y;
    int bm = blockIdx.x >> 3, bn = blockIdx.x & 7;
    if (y == 0)      gemm128_core<0>(Xq, Wq, bq, Qh, bm, bn, LOG2E);
    else if (y == 1) gemm128_core<0>(Xk, Wk, bk, Kh, bm, bn, 1.0f);
    else             gemm128_core<2>(Xv, Wv, bv, Vt, bm, bn, 1.0f);
}

// ---------------- 64x128 GEMM for output projection (fp32 out) ----------------
__global__ __launch_bounds__(256) void ogemm_kernel(const bf16* __restrict__ A,
                                                    const bf16* __restrict__ Wt,
                                                    const float* __restrict__ bias,
                                                    float* __restrict__ Out) {
    int bm = blockIdx.x >> 3, bn = blockIdx.x & 7;   // 64 x 8 tiles
    __shared__ __align__(16) bf16 la[64 * 32];
    __shared__ __align__(16) bf16 lb[128 * 32];
    int tid = threadIdx.x;
    int w = tid >> 6, lane = tid & 63;
    int quad = lane >> 4, col = lane & 15;
    int m0 = bm * 64, n0 = bn * 128;
    f32x4 acc[4][2];
    f32x4 z = {0.f, 0.f, 0.f, 0.f};
    #pragma unroll
    for (int i = 0; i < 4; ++i) { acc[i][0] = z; acc[i][1] = z; }
    int srow = lane >> 2;
    int skc = (lane & 3) * 8;
    for (int kt = 0; kt < 32; ++kt) {
        int kk = kt * 32;
        __syncthreads();
        g2l16(A + (size_t)(m0 + w * 16 + srow) * 1024 + kk + skc, &la[w * 512]);
        #pragma unroll
        for (int rr = 0; rr < 2; ++rr) {
            int ch = rr * 4 + w;
            g2l16(Wt + (size_t)(n0 + ch * 16 + srow) * 1024 + kk + skc, &lb[ch * 512]);
        }
        __syncthreads();
        bf16x8 af[4], bfr[2];
        #pragma unroll
        for (int mt = 0; mt < 4; ++mt)
            af[mt] = *(const bf16x8*)&la[(mt * 16 + col) * 32 + quad * 8];
        #pragma unroll
        for (int nt = 0; nt < 2; ++nt)
            bfr[nt] = *(const bf16x8*)&lb[(w * 32 + nt * 16 + col) * 32 + quad * 8];
        #pragma unroll
        for (int mt = 0; mt < 4; ++mt)
            #pragma unroll
            for (int nt = 0; nt < 2; ++nt)
                acc[mt][nt] = __builtin_amdgcn_mfma_f32_16x16x32_bf16(
                    af[mt], bfr[nt], acc[mt][nt], 0, 0, 0);
    }
    float bia[2];
    bia[0] = bias[n0 + w * 32 + col];
    bia[1] = bias[n0 + w * 32 + 16 + col];
    #pragma unroll
    for (int mt = 0; mt < 4; ++mt)
        #pragma unroll
        for (int nt = 0; nt < 2; ++nt)
            #pragma unroll
            for (int r = 0; r < 4; ++r)
                Out[(size_t)(m0 + mt * 16 + quad * 4 + r) * 1024 +
                    n0 + w * 32 + nt * 16 + col] = acc[mt][nt][r] + bia[nt];
}

// ---------------- flash attention ----------------
// 32 q-rows/wave, 128/block. p = exp2(s) (log2e folded into Q projection; no
// offset needed, |s| << 127). Mask: 1 cndmask per 64 elems via inverse_ballot of
// pre-transposed rmb words (scalar loads). Row sums: P x ones via MFMA.
// Staging: R3's proven 2-barrier single-buffer K/V loop.
__global__ __launch_bounds__(256) void attn_kernel(const bf16* __restrict__ Qh,
                                                   const bf16* __restrict__ Kh,
                                                   const bf16* __restrict__ Vt,
                                                   const unsigned long long* __restrict__ rmb,
                                                   bf16* __restrict__ att) {
    int bh = blockIdx.x, qt = blockIdx.y;
    int b = bh >> 4, h = bh & 15;
    int q0 = qt * 128;
    __shared__ __align__(16) bf16 qs[128 * 64];    // swizzled [row][g^(row&7)]
    __shared__ __align__(16) bf16 ks[64 * 64];
    __shared__ __align__(16) bf16 vs[64 * 64];     // V^T tile, rows = d
    __shared__ __align__(16) bf16 ps[4 * 32 * 72]; // per-wave P [qrow][j], +8 pad
    int tid = threadIdx.x;
    int w = tid >> 6, lane = tid & 63;
    int quad = lane >> 4, col = lane & 15;
    int c7 = col & 7;
    int sr = lane >> 3;              // row-within-chunk for staging (8 rows/chunk)
    int sg = (lane & 7) ^ sr;        // swizzled d-group this lane fetches
    int swz0 = (quad ^ c7) * 8;      // k2=0 fragment offset (elements)
    int swz1 = ((4 + quad) ^ c7) * 8;

    // mask word base for this wave's first 16-row group (wave-uniform -> s_loads)
    int mofs = __builtin_amdgcn_readfirstlane((qt * 8 + w * 2) * 512);

    // stage Q tile once: 16 chunks of 8 rows; wave w stages its own rows w*32..+32
    #pragma unroll
    for (int i = 0; i < 4; ++i) {
        int ch = w * 4 + i;
        g2l16(Qh + ((size_t)bh * 2048 + q0 + ch * 8 + sr) * 64 + sg * 8, &qs[ch * 512]);
    }
    __syncthreads();
    bf16x8 aq[2][2];
    #pragma unroll
    for (int mt = 0; mt < 2; ++mt) {
        aq[mt][0] = *(const bf16x8*)&qs[(w * 32 + mt * 16 + col) * 64 + swz0];
        aq[mt][1] = *(const bf16x8*)&qs[(w * 32 + mt * 16 + col) * 64 + swz1];
    }
    bf16x8 onesf;
    #pragma unroll
    for (int i = 0; i < 8; ++i) onesf[i] = (bf16)1.0f;

    f32x4 z = {0.f, 0.f, 0.f, 0.f};
    f32x4 O[2][4], R[2];
    #pragma unroll
    for (int mt = 0; mt < 2; ++mt) {
        R[mt] = z;
        #pragma unroll
        for (int i = 0; i < 4; ++i) O[mt][i] = z;
    }

    for (int kt = 0; kt < 32; ++kt) {
        __syncthreads();
        #pragma unroll
        for (int rr = 0; rr < 2; ++rr) {
            int ch = rr * 4 + w;
            int r = ch * 8 + sr;
            g2l16(Kh + ((size_t)bh * 2048 + kt * 64 + r) * 64 + sg * 8, &ks[ch * 512]);
            g2l16(Vt + ((size_t)bh * 64 + r) * 2048 + kt * 64 + sg * 8, &vs[ch * 512]);
        }
        __syncthreads();

        // S = Q K^T : 32q x 64j per wave, each bk read feeds 2 MFMAs
        f32x4 s[2][4];
        #pragma unroll
        for (int nt = 0; nt < 4; ++nt) {
            s[0][nt] = z; s[1][nt] = z;
            bf16x8 bk0 = *(const bf16x8*)&ks[(nt * 16 + col) * 64 + swz0];
            s[0][nt] = __builtin_amdgcn_mfma_f32_16x16x32_bf16(aq[0][0], bk0, s[0][nt], 0, 0, 0);
            s[1][nt] = __builtin_amdgcn_mfma_f32_16x16x32_bf16(aq[1][0], bk0, s[1][nt], 0, 0, 0);
            bf16x8 bk1 = *(const bf16x8*)&ks[(nt * 16 + col) * 64 + swz1];
            s[0][nt] = __builtin_amdgcn_mfma_f32_16x16x32_bf16(aq[0][1], bk1, s[0][nt], 0, 0, 0);
            s[1][nt] = __builtin_amdgcn_mfma_f32_16x16x32_bf16(aq[1][1], bk1, s[1][nt], 0, 0, 0);
        }

        // p = exp2(s); zero masked lanes (1 cndmask per word); P -> per-wave LDS
        #pragma unroll
        for (int mt = 0; mt < 2; ++mt) {
            const unsigned long long* mw = rmb + mofs + mt * 512 + kt * 16;
            #pragma unroll
            for (int r = 0; r < 4; ++r) {
                #pragma unroll
                for (int nt = 0; nt < 4; ++nt) {
                    float p = __builtin_amdgcn_exp2f(s[mt][nt][r]);
                    if (lane_masked(mw[r * 4 + nt])) p = 0.0f;
                    ps[w * 2304 + (mt * 16 + quad * 4 + r) * 72 + nt * 16 + col] = (bf16)p;
                }
            }
        }

        // O += P V ; R += P * ones (row sums) — wave-synchronous ps round-trip
        bf16x8 ap[2][2];
        #pragma unroll
        for (int mt = 0; mt < 2; ++mt) {
            ap[mt][0] = *(const bf16x8*)&ps[w * 2304 + (mt * 16 + col) * 72 + quad * 8];
            ap[mt][1] = *(const bf16x8*)&ps[w * 2304 + (mt * 16 + col) * 72 + 32 + quad * 8];
        }
        #pragma unroll
        for (int dt = 0; dt < 4; ++dt) {
            bf16x8 bv0 = *(const bf16x8*)&vs[(dt * 16 + col) * 64 + swz0];
            O[0][dt] = __builtin_amdgcn_mfma_f32_16x16x32_bf16(ap[0][0], bv0, O[0][dt], 0, 0, 0);
            O[1][dt] = __builtin_amdgcn_mfma_f32_16x16x32_bf16(ap[1][0], bv0, O[1][dt], 0, 0, 0);
            bf16x8 bv1 = *(const bf16x8*)&vs[(dt * 16 + col) * 64 + swz1];
            O[0][dt] = __builtin_amdgcn_mfma_f32_16x16x32_bf16(ap[0][1], bv1, O[0][dt], 0, 0, 0);
            O[1][dt] = __builtin_amdgcn_mfma_f32_16x16x32_bf16(ap[1][1], bv1, O[1][dt], 0, 0, 0);
        }
        #pragma unroll
        for (int mt = 0; mt < 2; ++mt) {
            R[mt] = __builtin_amdgcn_mfma_f32_16x16x32_bf16(ap[mt][0], onesf, R[mt], 0, 0, 0);
            R[mt] = __builtin_amdgcn_mfma_f32_16x16x32_bf16(ap[mt][1], onesf, R[mt], 0, 0, 0);
        }
    }

    // epilogue: O/l, combined-head layout [b][l][h*64+d]; R holds row sums
    #pragma unroll
    for (int mt = 0; mt < 2; ++mt) {
        #pragma unroll
        for (int r = 0; r < 4; ++r) {
            float rsv = R[mt][r];
            float inv = (rsv > 0.f) ? 1.0f / rsv : 0.f;
            int qg = q0 + w * 32 + mt * 16 + quad * 4 + r;
            #pragma unroll
            for (int dt = 0; dt < 4; ++dt) {
                float ov = O[mt][dt][r] * inv;
                att[((size_t)b * 2048 + qg) * 1024 + h * 64 + dt * 16 + col] = (bf16)ov;
            }
        }
    }
}

extern "C" void kernel_launch(void* const* d_in, const int* in_sizes, int n_in,
                              void* d_out, int out_size, void* d_ws, size_t ws_size,
                              hipStream_t stream) {
    (void)in_sizes; (void)n_in; (void)out_size; (void)ws_size;
    const float* query = (const float*)d_in[0];
    const float* key_  = (const float*)d_in[1];
    const float* value = (const float*)d_in[2];
    const void*  mask  = d_in[3];
    const float* W_q = (const float*)d_in[4];
    const float* b_q = (const float*)d_in[5];
    const float* W_k = (const float*)d_in[6];
    const float* b_k = (const float*)d_in[7];
    const float* W_v = (const float*)d_in[8];
    const float* b_v = (const float*)d_in[9];
    const float* W_o = (const float*)d_in[10];
    const float* b_o = (const float*)d_in[11];

    char* ws = (char*)d_ws;
    bf16* Xq  = (bf16*)(ws + 0);
    bf16* Xk  = (bf16*)(ws + 8388608);
    bf16* Xv  = (bf16*)(ws + 16777216);
    bf16* Wtq = (bf16*)(ws + 25165824);
    bf16* Wtk = (bf16*)(ws + 27262976);
    bf16* Wtv = (bf16*)(ws + 29360128);
    bf16* Wto = (bf16*)(ws + 31457280);
    bf16* Qh  = (bf16*)(ws + 33554432);
    bf16* Kh  = (bf16*)(ws + 41943040);
    bf16* Vt  = (bf16*)(ws + 50331648);
    bf16* att = (bf16*)(ws + 58720256);
    unsigned long long* mb  = (unsigned long long*)(ws + 67108864);
    unsigned long long* rmb = (unsigned long long*)(ws + 67633152);
    int* flag = (int*)(ws + 68157440);

    hipMemsetAsync(flag, 0, 4, stream);
    mdetect_kernel<<<4096, 256, 0, stream>>>((const unsigned int*)mask, flag);
    mpack_kernel<<<16384, 256, 0, stream>>>(mask, mb, flag);
    rpack_kernel<<<1024, 256, 0, stream>>>(mb, rmb);

    cvt3_kernel<<<dim3(4096, 3), 256, 0, stream>>>(query, key_, value, Xq, Xk, Xv);
    wtrans_kernel<<<dim3(256, 4), 256, 0, stream>>>(W_q, W_k, W_v, W_o, Wtq, Wtk, Wtv, Wto);

    qkv_kernel<<<dim3(256, 3), 256, 0, stream>>>(Xq, Xk, Xv, Wtq, Wtk, Wtv,
                                                 b_q, b_k, b_v, Qh, Kh, Vt);
    attn_kernel<<<dim3(32, 16), 256, 0, stream>>>(Qh, Kh, Vt, rmb, att);
    ogemm_kernel<<<512, 256, 0, stream>>>(att, Wto, b_o, (float*)d_out);
}

// Round 6
// 271.764 us; speedup vs baseline: 1.0866x; 1.0866x over previous
//
#include <hip/hip_runtime.h>
#include <hip/hip_bf16.h>
#include <stdint.h>

// MultiHeadAttentionNoScale: B=2, L=2048, D=1024, H=16, dk=64.
// R6: attn stall fix — q-tile 64 / block 128 / grid 1024 (4 independent barrier
//     domains per CU instead of 2, so one block's barrier+memory stalls are
//     covered by the other blocks' compute). Q staged through ks (LDS 25.6KB).
//     Keeps R5's proven semantics: rmb scalar mask, ones-MFMA row sums,
//     single-buffered 2-barrier K/V staging.

typedef __bf16 bf16;
typedef __bf16 bf16x8 __attribute__((ext_vector_type(8)));
typedef float f32x4 __attribute__((ext_vector_type(4)));

#define AS1 __attribute__((address_space(1)))
#define AS3 __attribute__((address_space(3)))

__device__ __forceinline__ void g2l16(const void* g, void* l) {
    // async global->LDS, 16B per lane; LDS dest = wave-uniform base + lane*16
    __builtin_amdgcn_global_load_lds((AS1 void*)g, (AS3 void*)l, 16, 0, 0);
}

// true iff this lane's bit is set in wave-uniform mask m
__device__ __forceinline__ bool lane_masked(unsigned long long m) {
#if __has_builtin(__builtin_amdgcn_inverse_ballot_w64)
    return __builtin_amdgcn_inverse_ballot_w64(m);
#else
    return (m >> (threadIdx.x & 63)) & 1ull;
#endif
}

#define LOG2E 1.44269504088896f

// ---------------- fp32 -> bf16 convert (3 tensors, one launch) ----------------
__global__ __launch_bounds__(256) void cvt3_kernel(const float* __restrict__ a0,
                                                   const float* __restrict__ a1,
                                                   const float* __restrict__ a2,
                                                   bf16* o0, bf16* o1, bf16* o2) {
    int y = blockIdx.y;
    const float* in = (y == 0) ? a0 : (y == 1) ? a1 : a2;
    bf16* out = (y == 0) ? o0 : (y == 1) ? o1 : o2;
    int idx = blockIdx.x * 256 + threadIdx.x;
    float4 v = ((const float4*)in)[idx];
    __align__(8) bf16 o[4];
    o[0] = (bf16)v.x; o[1] = (bf16)v.y; o[2] = (bf16)v.z; o[3] = (bf16)v.w;
    *(uint2*)(out + (size_t)idx * 4) = *(const uint2*)o;
}

// ---------------- mask representation detect (int32 / uint8 / fp32) ----------------
__global__ __launch_bounds__(256) void mdetect_kernel(const unsigned int* __restrict__ w,
                                                      int* __restrict__ flag) {
    int idx = blockIdx.x * 256 + threadIdx.x;
    unsigned v = w[idx];
    int f = 0;
    if (v == 0x3F800000u) f = 2;        // float 1.0 pattern -> fp32 mask
    else if (v > 1u) f = 1;             // bytes packed -> uint8 mask
    unsigned long long b1 = __ballot(f & 1);
    unsigned long long b2 = __ballot(f & 2);
    if ((threadIdx.x & 63) == 0) {
        int agg = (b1 ? 1 : 0) | (b2 ? 2 : 0);
        if (agg) atomicOr(flag, agg);
    }
}

// ---------------- mask -> bitmask mb[row][kword], bit=1 means masked ----------------
__global__ __launch_bounds__(256) void mpack_kernel(const void* __restrict__ mask,
                                                    unsigned long long* __restrict__ mb,
                                                    const int* __restrict__ flag) {
    int idx = blockIdx.x * 256 + threadIdx.x;
    int f = *flag;
    bool v;
    if (f & 2)      v = ((const float*)mask)[idx] != 0.0f;
    else if (f & 1) v = ((const unsigned char*)mask)[idx] != 0;
    else            v = ((const int*)mask)[idx] != 0;
    unsigned long long b = __ballot(v);
    if ((threadIdx.x & 63) == 0) mb[idx >> 6] = b;
}

// ---------------- mb -> rmb: lane-bit layout for attn's C-fragment ----------------
// word(task=qg*32+kt, r, nt): bit(lane) = mask[qg*16 + (lane>>4)*4 + r][kt*64 + nt*16 + (lane&15)]
__global__ __launch_bounds__(256) void rpack_kernel(const unsigned long long* __restrict__ mb,
                                                    unsigned long long* __restrict__ rmb) {
    int task = blockIdx.x * 4 + (threadIdx.x >> 6);   // 0..4095
    int qg = task >> 5, kt = task & 31;
    int lane = threadIdx.x & 63, quad = lane >> 4, col = lane & 15;
    #pragma unroll
    for (int r = 0; r < 4; ++r) {
        unsigned long long wrow = mb[(size_t)(qg * 16 + quad * 4 + r) * 32 + kt];
        #pragma unroll
        for (int nt = 0; nt < 4; ++nt) {
            unsigned long long b = __ballot(((wrow >> (nt * 16 + col)) & 1ull) != 0);
            if (lane == 0) rmb[(size_t)task * 16 + r * 4 + nt] = b;
        }
    }
}

// ---------------- W [k][n] fp32 -> Wt [n][k] bf16 (64x64 LDS tile transpose) ----------------
__global__ __launch_bounds__(256) void wtrans_kernel(const float* W0, const float* W1,
                                                     const float* W2, const float* W3,
                                                     bf16* T0, bf16* T1, bf16* T2, bf16* T3) {
    const float* W; bf16* T;
    int y = blockIdx.y;
    if (y == 0)      { W = W0; T = T0; }
    else if (y == 1) { W = W1; T = T1; }
    else if (y == 2) { W = W2; T = T2; }
    else             { W = W3; T = T3; }
    int tx = blockIdx.x & 15, ty = blockIdx.x >> 4;
    int n0 = tx * 64, k0 = ty * 64;
    __shared__ __align__(16) bf16 t[64 * 72];   // [k][n], +8 pad
    int tid = threadIdx.x;
    #pragma unroll
    for (int rr = 0; rr < 4; ++rr) {
        int idx = rr * 256 + tid;
        int r = idx >> 4, c4 = (idx & 15) * 4;
        float4 v = *(const float4*)(W + (size_t)(k0 + r) * 1024 + n0 + c4);
        __align__(8) bf16 o[4];
        o[0] = (bf16)v.x; o[1] = (bf16)v.y; o[2] = (bf16)v.z; o[3] = (bf16)v.w;
        *(uint2*)&t[r * 72 + c4] = *(const uint2*)o;
    }
    __syncthreads();
    #pragma unroll
    for (int rr = 0; rr < 2; ++rr) {
        int idx = rr * 256 + tid;
        int n = idx >> 3, kc = (idx & 7) * 8;
        __align__(16) bf16 o[8];
        #pragma unroll
        for (int j = 0; j < 8; ++j) o[j] = t[(kc + j) * 72 + n];
        *(uint4*)(T + (size_t)(n0 + n) * 1024 + k0 + kc) = *(const uint4*)o;
    }
}

// ---------------- 128x128 bt-GEMM core ----------------
// C[m,n] = (sum_k A[m,k]*Bt[n,k] + bias[n]) * scale
// MODE 0: bf16 head-layout [b][h][l][dk]; MODE 2: bf16 V^T [b][h][dk][l]
template <int MODE>
__device__ __forceinline__ void gemm128_core(const bf16* __restrict__ A,
                                             const bf16* __restrict__ Bt,
                                             const float* __restrict__ bias,
                                             void* __restrict__ Out, int bm, int bn,
                                             float scale) {
    __shared__ __align__(16) bf16 la[128 * 32];
    __shared__ __align__(16) bf16 lb[128 * 32];
    int tid = threadIdx.x;
    int w = tid >> 6, lane = tid & 63;
    int quad = lane >> 4, col = lane & 15;
    int wm = w >> 1, wn = w & 1;
    int m0 = bm * 128, n0 = bn * 128;
    f32x4 acc[4][4];
    f32x4 z = {0.f, 0.f, 0.f, 0.f};
    #pragma unroll
    for (int i = 0; i < 4; ++i)
        #pragma unroll
        for (int j = 0; j < 4; ++j) acc[i][j] = z;
    int srow = lane >> 2;
    int skc = (lane & 3) * 8;
    for (int kt = 0; kt < 32; ++kt) {
        int kk = kt * 32;
        __syncthreads();
        #pragma unroll
        for (int rr = 0; rr < 2; ++rr) {
            int ch = rr * 4 + w;
            int row = ch * 16 + srow;
            g2l16(A + (size_t)(m0 + row) * 1024 + kk + skc, &la[ch * 512]);
            g2l16(Bt + (size_t)(n0 + row) * 1024 + kk + skc, &lb[ch * 512]);
        }
        __syncthreads();
        bf16x8 af[4], bfr[4];
        #pragma unroll
        for (int mt = 0; mt < 4; ++mt)
            af[mt] = *(const bf16x8*)&la[(wm * 64 + mt * 16 + col) * 32 + quad * 8];
        #pragma unroll
        for (int nt = 0; nt < 4; ++nt)
            bfr[nt] = *(const bf16x8*)&lb[(wn * 64 + nt * 16 + col) * 32 + quad * 8];
        #pragma unroll
        for (int mt = 0; mt < 4; ++mt)
            #pragma unroll
            for (int nt = 0; nt < 4; ++nt)
                acc[mt][nt] = __builtin_amdgcn_mfma_f32_16x16x32_bf16(
                    af[mt], bfr[nt], acc[mt][nt], 0, 0, 0);
    }
    float bia[4];
    #pragma unroll
    for (int nt = 0; nt < 4; ++nt) bia[nt] = bias[n0 + wn * 64 + nt * 16 + col];
    #pragma unroll
    for (int mt = 0; mt < 4; ++mt) {
        #pragma unroll
        for (int nt = 0; nt < 4; ++nt) {
            #pragma unroll
            for (int r = 0; r < 4; ++r) {
                int m = m0 + wm * 64 + mt * 16 + quad * 4 + r;
                int n = n0 + wn * 64 + nt * 16 + col;
                float v = (acc[mt][nt][r] + bia[nt]) * scale;
                if (MODE == 0) {
                    int b = m >> 11, l = m & 2047, h = n >> 6, d = n & 63;
                    ((bf16*)Out)[(((size_t)b * 16 + h) * 2048 + l) * 64 + d] = (bf16)v;
                } else {
                    int b = m >> 11, l = m & 2047, h = n >> 6, d = n & 63;
                    ((bf16*)Out)[(((size_t)b * 16 + h) * 64 + d) * 2048 + l] = (bf16)v;
                }
            }
        }
    }
}

// Q scaled by log2e (folded softmax base conversion); K,V unscaled; V -> V^T layout
__global__ __launch_bounds__(256) void qkv_kernel(
    const bf16* Xq, const bf16* Xk, const bf16* Xv,
    const bf16* Wq, const bf16* Wk, const bf16* Wv,
    const float* bq, const float* bk, const float* bv,
    bf16* Qh, bf16* Kh, bf16* Vt) {
    int y = blockIdx.y;
    int bm = blockIdx.x >> 3, bn = blockIdx.x & 7;
    if (y == 0)      gemm128_core<0>(Xq, Wq, bq, Qh, bm, bn, LOG2E);
    else if (y == 1) gemm128_core<0>(Xk, Wk, bk, Kh, bm, bn, 1.0f);
    else             gemm128_core<2>(Xv, Wv, bv, Vt, bm, bn, 1.0f);
}

// ---------------- 64x128 GEMM for output projection (fp32 out) ----------------
__global__ __launch_bounds__(256) void ogemm_kernel(const bf16* __restrict__ A,
                                                    const bf16* __restrict__ Wt,
                                                    const float* __restrict__ bias,
                                                    float* __restrict__ Out) {
    int bm = blockIdx.x >> 3, bn = blockIdx.x & 7;   // 64 x 8 tiles
    __shared__ __align__(16) bf16 la[64 * 32];
    __shared__ __align__(16) bf16 lb[128 * 32];
    int tid = threadIdx.x;
    int w = tid >> 6, lane = tid & 63;
    int quad = lane >> 4, col = lane & 15;
    int m0 = bm * 64, n0 = bn * 128;
    f32x4 acc[4][2];
    f32x4 z = {0.f, 0.f, 0.f, 0.f};
    #pragma unroll
    for (int i = 0; i < 4; ++i) { acc[i][0] = z; acc[i][1] = z; }
    int srow = lane >> 2;
    int skc = (lane & 3) * 8;
    for (int kt = 0; kt < 32; ++kt) {
        int kk = kt * 32;
        __syncthreads();
        g2l16(A + (size_t)(m0 + w * 16 + srow) * 1024 + kk + skc, &la[w * 512]);
        #pragma unroll
        for (int rr = 0; rr < 2; ++rr) {
            int ch = rr * 4 + w;
            g2l16(Wt + (size_t)(n0 + ch * 16 + srow) * 1024 + kk + skc, &lb[ch * 512]);
        }
        __syncthreads();
        bf16x8 af[4], bfr[2];
        #pragma unroll
        for (int mt = 0; mt < 4; ++mt)
            af[mt] = *(const bf16x8*)&la[(mt * 16 + col) * 32 + quad * 8];
        #pragma unroll
        for (int nt = 0; nt < 2; ++nt)
            bfr[nt] = *(const bf16x8*)&lb[(w * 32 + nt * 16 + col) * 32 + quad * 8];
        #pragma unroll
        for (int mt = 0; mt < 4; ++mt)
            #pragma unroll
            for (int nt = 0; nt < 2; ++nt)
                acc[mt][nt] = __builtin_amdgcn_mfma_f32_16x16x32_bf16(
                    af[mt], bfr[nt], acc[mt][nt], 0, 0, 0);
    }
    float bia[2];
    bia[0] = bias[n0 + w * 32 + col];
    bia[1] = bias[n0 + w * 32 + 16 + col];
    #pragma unroll
    for (int mt = 0; mt < 4; ++mt)
        #pragma unroll
        for (int nt = 0; nt < 2; ++nt)
            #pragma unroll
            for (int r = 0; r < 4; ++r)
                Out[(size_t)(m0 + mt * 16 + quad * 4 + r) * 1024 +
                    n0 + w * 32 + nt * 16 + col] = acc[mt][nt][r] + bia[nt];
}

// ---------------- flash attention ----------------
// Block = 128 threads (2 waves), q-tile 64 (32 q-rows/wave, mt in {0,1}).
// Grid 32 bh x 32 qt = 1024 blocks = 4 independent barrier domains per CU.
// Q staged through ks (dead after A-frag hoist). p = exp2(s) (log2e folded into
// Q projection). Mask: 1 cndmask per 64 elems via inverse_ballot of rmb words.
// Row sums: P x ones MFMA. Single-buffer 2-barrier K/V staging (proven).
__global__ __launch_bounds__(128) void attn_kernel(const bf16* __restrict__ Qh,
                                                   const bf16* __restrict__ Kh,
                                                   const bf16* __restrict__ Vt,
                                                   const unsigned long long* __restrict__ rmb,
                                                   bf16* __restrict__ att) {
    int bh = blockIdx.x, qt = blockIdx.y;
    int b = bh >> 4, h = bh & 15;
    int q0 = qt * 64;
    __shared__ __align__(16) bf16 ks[64 * 64];     // swizzled [row][g^(row&7)]; Q first
    __shared__ __align__(16) bf16 vs[64 * 64];     // V^T tile, rows = d
    __shared__ __align__(16) bf16 ps[2 * 32 * 72]; // per-wave P [qrow][j], +8 pad
    int tid = threadIdx.x;
    int w = tid >> 6, lane = tid & 63;             // w in {0,1}
    int quad = lane >> 4, col = lane & 15;
    int c7 = col & 7;
    int sr = lane >> 3;              // row-within-chunk for staging (8 rows/chunk)
    int sg = (lane & 7) ^ sr;        // swizzled d-group this lane fetches
    int swz0 = (quad ^ c7) * 8;      // k2=0 fragment offset (elements)
    int swz1 = ((4 + quad) ^ c7) * 8;

    // mask word base for this wave's first 16-row group (wave-uniform -> s_loads)
    int mofs = __builtin_amdgcn_readfirstlane((qt * 4 + w * 2) * 512);

    // stage Q tile (64 rows) through ks; wave w stages chunks w*4..w*4+3
    #pragma unroll
    for (int i = 0; i < 4; ++i) {
        int ch = w * 4 + i;
        g2l16(Qh + ((size_t)bh * 2048 + q0 + ch * 8 + sr) * 64 + sg * 8, &ks[ch * 512]);
    }
    __syncthreads();
    bf16x8 aq[2][2];
    #pragma unroll
    for (int mt = 0; mt < 2; ++mt) {
        aq[mt][0] = *(const bf16x8*)&ks[(w * 32 + mt * 16 + col) * 64 + swz0];
        aq[mt][1] = *(const bf16x8*)&ks[(w * 32 + mt * 16 + col) * 64 + swz1];
    }
    bf16x8 onesf;
    #pragma unroll
    for (int i = 0; i < 8; ++i) onesf[i] = (bf16)1.0f;

    f32x4 z = {0.f, 0.f, 0.f, 0.f};
    f32x4 O[2][4], R[2];
    #pragma unroll
    for (int mt = 0; mt < 2; ++mt) {
        R[mt] = z;
        #pragma unroll
        for (int i = 0; i < 4; ++i) O[mt][i] = z;
    }

    for (int kt = 0; kt < 32; ++kt) {
        __syncthreads();   // (first iter: protects ks Q-reads before overwrite)
        #pragma unroll
        for (int i = 0; i < 4; ++i) {
            int ch = w * 4 + i;
            int r = ch * 8 + sr;
            g2l16(Kh + ((size_t)bh * 2048 + kt * 64 + r) * 64 + sg * 8, &ks[ch * 512]);
            g2l16(Vt + ((size_t)bh * 64 + r) * 2048 + kt * 64 + sg * 8, &vs[ch * 512]);
        }
        __syncthreads();

        // S = Q K^T : 32q x 64j per wave, each bk read feeds 2 MFMAs
        f32x4 s[2][4];
        #pragma unroll
        for (int nt = 0; nt < 4; ++nt) {
            s[0][nt] = z; s[1][nt] = z;
            bf16x8 bk0 = *(const bf16x8*)&ks[(nt * 16 + col) * 64 + swz0];
            s[0][nt] = __builtin_amdgcn_mfma_f32_16x16x32_bf16(aq[0][0], bk0, s[0][nt], 0, 0, 0);
            s[1][nt] = __builtin_amdgcn_mfma_f32_16x16x32_bf16(aq[1][0], bk0, s[1][nt], 0, 0, 0);
            bf16x8 bk1 = *(const bf16x8*)&ks[(nt * 16 + col) * 64 + swz1];
            s[0][nt] = __builtin_amdgcn_mfma_f32_16x16x32_bf16(aq[0][1], bk1, s[0][nt], 0, 0, 0);
            s[1][nt] = __builtin_amdgcn_mfma_f32_16x16x32_bf16(aq[1][1], bk1, s[1][nt], 0, 0, 0);
        }

        // p = exp2(s); zero masked lanes (1 cndmask per word); P -> per-wave LDS
        #pragma unroll
        for (int mt = 0; mt < 2; ++mt) {
            const unsigned long long* mw = rmb + mofs + mt * 512 + kt * 16;
            #pragma unroll
            for (int r = 0; r < 4; ++r) {
                #pragma unroll
                for (int nt = 0; nt < 4; ++nt) {
                    float p = __builtin_amdgcn_exp2f(s[mt][nt][r]);
                    if (lane_masked(mw[r * 4 + nt])) p = 0.0f;
                    ps[w * 2304 + (mt * 16 + quad * 4 + r) * 72 + nt * 16 + col] = (bf16)p;
                }
            }
        }

        // O += P V ; R += P * ones (row sums) — wave-synchronous ps round-trip
        bf16x8 ap[2][2];
        #pragma unroll
        for (int mt = 0; mt < 2; ++mt) {
            ap[mt][0] = *(const bf16x8*)&ps[w * 2304 + (mt * 16 + col) * 72 + quad * 8];
            ap[mt][1] = *(const bf16x8*)&ps[w * 2304 + (mt * 16 + col) * 72 + 32 + quad * 8];
        }
        #pragma unroll
        for (int dt = 0; dt < 4; ++dt) {
            bf16x8 bv0 = *(const bf16x8*)&vs[(dt * 16 + col) * 64 + swz0];
            O[0][dt] = __builtin_amdgcn_mfma_f32_16x16x32_bf16(ap[0][0], bv0, O[0][dt], 0, 0, 0);
            O[1][dt] = __builtin_amdgcn_mfma_f32_16x16x32_bf16(ap[1][0], bv0, O[1][dt], 0, 0, 0);
            bf16x8 bv1 = *(const bf16x8*)&vs[(dt * 16 + col) * 64 + swz1];
            O[0][dt] = __builtin_amdgcn_mfma_f32_16x16x32_bf16(ap[0][1], bv1, O[0][dt], 0, 0, 0);
            O[1][dt] = __builtin_amdgcn_mfma_f32_16x16x32_bf16(ap[1][1], bv1, O[1][dt], 0, 0, 0);
        }
        #pragma unroll
        for (int mt = 0; mt < 2; ++mt) {
            R[mt] = __builtin_amdgcn_mfma_f32_16x16x32_bf16(ap[mt][0], onesf, R[mt], 0, 0, 0);
            R[mt] = __builtin_amdgcn_mfma_f32_16x16x32_bf16(ap[mt][1], onesf, R[mt], 0, 0, 0);
        }
    }

    // epilogue: O/l, combined-head layout [b][l][h*64+d]; R holds row sums
    #pragma unroll
    for (int mt = 0; mt < 2; ++mt) {
        #pragma unroll
        for (int r = 0; r < 4; ++r) {
            float rsv = R[mt][r];
            float inv = (rsv > 0.f) ? 1.0f / rsv : 0.f;
            int qg = q0 + w * 32 + mt * 16 + quad * 4 + r;
            #pragma unroll
            for (int dt = 0; dt < 4; ++dt) {
                float ov = O[mt][dt][r] * inv;
                att[((size_t)b * 2048 + qg) * 1024 + h * 64 + dt * 16 + col] = (bf16)ov;
            }
        }
    }
}

extern "C" void kernel_launch(void* const* d_in, const int* in_sizes, int n_in,
                              void* d_out, int out_size, void* d_ws, size_t ws_size,
                              hipStream_t stream) {
    (void)in_sizes; (void)n_in; (void)out_size; (void)ws_size;
    const float* query = (const float*)d_in[0];
    const float* key_  = (const float*)d_in[1];
    const float* value = (const float*)d_in[2];
    const void*  mask  = d_in[3];
    const float* W_q = (const float*)d_in[4];
    const float* b_q = (const float*)d_in[5];
    const float* W_k = (const float*)d_in[6];
    const float* b_k = (const float*)d_in[7];
    const float* W_v = (const float*)d_in[8];
    const float* b_v = (const float*)d_in[9];
    const float* W_o = (const float*)d_in[10];
    const float* b_o = (const float*)d_in[11];

    char* ws = (char*)d_ws;
    bf16* Xq  = (bf16*)(ws + 0);
    bf16* Xk  = (bf16*)(ws + 8388608);
    bf16* Xv  = (bf16*)(ws + 16777216);
    bf16* Wtq = (bf16*)(ws + 25165824);
    bf16* Wtk = (bf16*)(ws + 27262976);
    bf16* Wtv = (bf16*)(ws + 29360128);
    bf16* Wto = (bf16*)(ws + 31457280);
    bf16* Qh  = (bf16*)(ws + 33554432);
    bf16* Kh  = (bf16*)(ws + 41943040);
    bf16* Vt  = (bf16*)(ws + 50331648);
    bf16* att = (bf16*)(ws + 58720256);
    unsigned long long* mb  = (unsigned long long*)(ws + 67108864);
    unsigned long long* rmb = (unsigned long long*)(ws + 67633152);
    int* flag = (int*)(ws + 68157440);

    hipMemsetAsync(flag, 0, 4, stream);
    mdetect_kernel<<<4096, 256, 0, stream>>>((const unsigned int*)mask, flag);
    mpack_kernel<<<16384, 256, 0, stream>>>(mask, mb, flag);
    rpack_kernel<<<1024, 256, 0, stream>>>(mb, rmb);

    cvt3_kernel<<<dim3(4096, 3), 256, 0, stream>>>(query, key_, value, Xq, Xk, Xv);
    wtrans_kernel<<<dim3(256, 4), 256, 0, stream>>>(W_q, W_k, W_v, W_o, Wtq, Wtk, Wtv, Wto);

    qkv_kernel<<<dim3(256, 3), 256, 0, stream>>>(Xq, Xk, Xv, Wtq, Wtk, Wtv,
                                                 b_q, b_k, b_v, Qh, Kh, Vt);
    attn_kernel<<<dim3(32, 32), 128, 0, stream>>>(Qh, Kh, Vt, rmb, att);
    ogemm_kernel<<<512, 256, 0, stream>>>(att, Wto, b_o, (float*)d_out);
}